// Round 4
// baseline (213.417 us; speedup 1.0000x reference)
//
#include <hip/hip_runtime.h>

// Inputs: [32,3,512,512] f32; pooled grid 128x128 per image.
#define HH 512
#define WW 512
#define PH 128
#define PW 128
#define CC 3

// Kernel 1: g[b,i,j] = (1/48) * sum_{c, 4x4 block} (orig - enh)
//
// One WAVE per (b, pooled-row i) strip. Key identity: a float4 wave-load of a
// contiguous half-row (1 KB) hands each lane exactly the 4 columns of ONE
// pooled cell: half 0 -> pooled col = lane, half 1 -> pooled col = 64+lane.
// So the full 3-channel 4x4 reduction is lane-local: 48 float4 loads walking
// six contiguous 8 KB chunks (+ mirror in enh), two accumulators, two
// coalesced dword stores. Loads staged per-channel (16 float4 in registers)
// for deep MLP; no LDS, no barriers.
__global__ void __launch_bounds__(256, 4)
pool_diff_kernel(const float* __restrict__ orig,
                 const float* __restrict__ enh,
                 float* __restrict__ g) {
    const int wid  = blockIdx.x * 4 + (threadIdx.x >> 6);  // strip = b*128 + i
    const int lane = threadIdx.x & 63;

    const int b = wid >> 7;
    const int i = wid & (PH - 1);

    const size_t img  = (size_t)HH * WW;                         // 262144
    const size_t base = (size_t)b * CC * img + (size_t)(4 * i) * WW;

    float s0 = 0.0f, s1 = 0.0f;   // pooled cols: lane, 64+lane

#pragma unroll
    for (int c = 0; c < CC; ++c) {
        const size_t cb = base + (size_t)c * img + (size_t)lane * 4;
        float4 ov[8], ev[8];
        // Stage all 16 loads of this channel before any use -> 16 in flight.
#pragma unroll
        for (int t = 0; t < 8; ++t) {          // t = r*2 + h
            const int r = t >> 1, h = t & 1;
            ov[t] = *(const float4*)(orig + cb + (size_t)r * WW + (size_t)h * 256);
        }
#pragma unroll
        for (int t = 0; t < 8; ++t) {
            const int r = t >> 1, h = t & 1;
            ev[t] = *(const float4*)(enh + cb + (size_t)r * WW + (size_t)h * 256);
        }
#pragma unroll
        for (int t = 0; t < 8; ++t) {
            const float d = (ov[t].x - ev[t].x) + (ov[t].y - ev[t].y)
                          + (ov[t].z - ev[t].z) + (ov[t].w - ev[t].w);
            if ((t & 1) == 0) s0 += d; else s1 += d;
        }
    }

    float* grow = g + (size_t)wid * PW;
    grow[lane]      = s0 * (1.0f / 48.0f);
    grow[lane + 64] = s1 * (1.0f / 48.0f);
}

// Kernel 2: loss[i,j] = sum over {l,r,u,d} of (g[i,j] - g_pad[neighbor])^2
// Zero padding: out-of-bounds neighbor contributes 0 (so diff = g[i,j]).
__global__ void __launch_bounds__(256)
stencil_loss_kernel(const float* __restrict__ g,
                    float* __restrict__ out, int total) {
    int idx = blockIdx.x * blockDim.x + threadIdx.x;
    if (idx >= total) return;
    int j = idx & (PW - 1);
    int i = (idx >> 7) & (PH - 1);

    float c = g[idx];
    float l = (j > 0)      ? g[idx - 1]  : 0.0f;
    float r = (j < PW - 1) ? g[idx + 1]  : 0.0f;
    float u = (i > 0)      ? g[idx - PW] : 0.0f;
    float d = (i < PH - 1) ? g[idx + PW] : 0.0f;

    float dl = c - l, dr = c - r, du = c - u, dd = c - d;
    out[idx] = dl * dl + dr * dr + du * du + dd * dd;
}

extern "C" void kernel_launch(void* const* d_in, const int* in_sizes, int n_in,
                              void* d_out, int out_size, void* d_ws, size_t ws_size,
                              hipStream_t stream) {
    const float* orig = (const float*)d_in[0];
    const float* enh  = (const float*)d_in[1];
    float* out = (float*)d_out;
    float* g   = (float*)d_ws;  // 32*128*128 floats = 2 MB scratch

    const int batch  = in_sizes[0] / (CC * HH * WW);  // 32
    const int strips = batch * PH;                    // 4096 waves
    const int total  = batch * PH * PW;               // 524288

    pool_diff_kernel<<<strips / 4, 256, 0, stream>>>(orig, enh, g);

    const int block = 256;
    const int grid = (total + block - 1) / block;     // 2048
    stencil_loss_kernel<<<grid, block, 0, stream>>>(g, out, total);
}

// Round 6
// 209.958 us; speedup vs baseline: 1.0165x; 1.0165x over previous
//
#include <hip/hip_runtime.h>

// Inputs: [32,3,512,512] f32; pooled grid 128x128 per image.
#define HH 512
#define WW 512
#define PH 128
#define PW 128
#define CC 3
#define STRIP_FLOATS (CC * 4 * WW)   // 6144 floats = 24 KB per input stream

// Async 16B global->LDS. LDS dest is wave-uniform base; HW adds lane*16.
__device__ __forceinline__ void async_cp16(const float* gsrc, float* ldst) {
    __builtin_amdgcn_global_load_lds(
        (const __attribute__((address_space(1))) void*)gsrc,
        (__attribute__((address_space(3))) void*)ldst,
        16, 0, 0);
}

// Kernel 1: g[b,i,j] = (1/48) * sum_{c, 4x4 block} (orig - enh)
// One block (4 waves) per strip (b, pooled row i). Stage the strip's
// 3 channels x 4 rows x 512 floats (both tensors) into LDS via
// global_load_lds width=16 (direct-to-LDS DMA, no VGPR writeback),
// 12 outstanding per wave. NOTE (R4 bug fix): channels are img=256K floats
// apart in global memory -- chunk k maps to channel c=k>>3, offset q=k&7;
// LDS layout is strip-contiguous: row (c*4+rr)*512 + col.
__global__ void __launch_bounds__(256)
pool_diff_kernel(const float* __restrict__ orig,
                 const float* __restrict__ enh,
                 float* __restrict__ g) {
    __shared__ __align__(16) float so[STRIP_FLOATS];
    __shared__ __align__(16) float se[STRIP_FLOATS];

    const int strip = blockIdx.x;            // b*128 + i
    const int wave  = threadIdx.x >> 6;
    const int lane  = threadIdx.x & 63;

    const int b = strip >> 7;
    const int i = strip & (PH - 1);
    const size_t img  = (size_t)HH * WW;     // 262144
    const size_t base = (size_t)b * CC * img + (size_t)(4 * i) * WW;

    // 24 chunks of 256 floats (1 KB) per stream; wave w stages chunks
    // w*6 .. w*6+5 of BOTH streams -> 12 outstanding per wave.
#pragma unroll
    for (int t = 0; t < 6; ++t) {
        const int k = wave * 6 + t;                        // 0..23
        const int c = k >> 3;                              // channel
        const int q = k & 7;                               // 256-float chunk in channel
        const size_t goff = base + (size_t)c * img + (size_t)q * 256 + (size_t)lane * 4;
        async_cp16(orig + goff, so + k * 256);
        async_cp16(enh  + goff, se + k * 256);
    }
    __syncthreads();   // compiler emits s_waitcnt vmcnt(0) before s_barrier

    // Reduction: thread j (0..127) owns pooled col j.
    // LDS strip layout: row = c*4 + rr, float index row*512 + col.
    if (threadIdx.x < PW) {
        const int j = threadIdx.x;
        float s = 0.0f;
#pragma unroll
        for (int row = 0; row < 12; ++row) {
            const float4 o4 = *(const float4*)(so + row * WW + 4 * j);
            const float4 e4 = *(const float4*)(se + row * WW + 4 * j);
            s += (o4.x - e4.x) + (o4.y - e4.y) + (o4.z - e4.z) + (o4.w - e4.w);
        }
        g[(size_t)strip * PW + j] = s * (1.0f / 48.0f);
    }
}

// Kernel 2: loss[i,j] = sum over {l,r,u,d} of (g[i,j] - g_pad[neighbor])^2
// Zero padding: out-of-bounds neighbor contributes 0 (so diff = g[i,j]).
__global__ void __launch_bounds__(256)
stencil_loss_kernel(const float* __restrict__ g,
                    float* __restrict__ out, int total) {
    int idx = blockIdx.x * blockDim.x + threadIdx.x;
    if (idx >= total) return;
    int j = idx & (PW - 1);
    int i = (idx >> 7) & (PH - 1);

    float c = g[idx];
    float l = (j > 0)      ? g[idx - 1]  : 0.0f;
    float r = (j < PW - 1) ? g[idx + 1]  : 0.0f;
    float u = (i > 0)      ? g[idx - PW] : 0.0f;
    float d = (i < PH - 1) ? g[idx + PW] : 0.0f;

    float dl = c - l, dr = c - r, du = c - u, dd = c - d;
    out[idx] = dl * dl + dr * dr + du * du + dd * dd;
}

extern "C" void kernel_launch(void* const* d_in, const int* in_sizes, int n_in,
                              void* d_out, int out_size, void* d_ws, size_t ws_size,
                              hipStream_t stream) {
    const float* orig = (const float*)d_in[0];
    const float* enh  = (const float*)d_in[1];
    float* out = (float*)d_out;
    float* g   = (float*)d_ws;  // 32*128*128 floats = 2 MB scratch

    const int batch  = in_sizes[0] / (CC * HH * WW);  // 32
    const int strips = batch * PH;                    // 4096 blocks
    const int total  = batch * PH * PW;               // 524288

    pool_diff_kernel<<<strips, 256, 0, stream>>>(orig, enh, g);

    const int block = 256;
    const int grid = (total + block - 1) / block;     // 2048
    stencil_loss_kernel<<<grid, block, 0, stream>>>(g, out, total);
}

// Round 7
// 194.373 us; speedup vs baseline: 1.0980x; 1.0802x over previous
//
#include <hip/hip_runtime.h>

// Inputs: [32,3,512,512] f32; pooled grid 128x128 per image.
#define HH 512
#define WW 512
#define PH 128
#define PW 128
#define CC 3

typedef float f32x4 __attribute__((ext_vector_type(4)));

// Kernel 1: g[b,i,j] = (1/48) * sum_{c, 4x4 block} (orig - enh)
// Persistent grid-stride waves (512 blocks = 2/CU, 4 cells/thread) with
// NON-TEMPORAL dwordx4 loads (nt bit: no cache allocation; these lines have
// provably zero reuse). All 24 loads per cell staged before accumulation.
// This is the last untried read mechanism; R0-R5 (5 structures) all clamp
// at 2.79 TB/s read.
__global__ void __launch_bounds__(256)
pool_diff_kernel(const float* __restrict__ orig,
                 const float* __restrict__ enh,
                 float* __restrict__ g, int total) {
    const int stride = gridDim.x * blockDim.x;
    for (int idx = blockIdx.x * blockDim.x + threadIdx.x; idx < total; idx += stride) {
        const int j = idx & (PW - 1);
        const int i = (idx >> 7) & (PH - 1);
        const int b = idx >> 14;

        const size_t img  = (size_t)HH * WW;          // 262144
        const size_t base = (size_t)b * CC * img + (size_t)(i * 4) * WW + (size_t)(j * 4);

        f32x4 ov[12], ev[12];
#pragma unroll
        for (int c = 0; c < CC; ++c) {
#pragma unroll
            for (int r = 0; r < 4; ++r) {
                const size_t off = base + (size_t)c * img + (size_t)r * WW;
                ov[c * 4 + r] = __builtin_nontemporal_load((const f32x4*)(orig + off));
            }
        }
#pragma unroll
        for (int c = 0; c < CC; ++c) {
#pragma unroll
            for (int r = 0; r < 4; ++r) {
                const size_t off = base + (size_t)c * img + (size_t)r * WW;
                ev[c * 4 + r] = __builtin_nontemporal_load((const f32x4*)(enh + off));
            }
        }

        float s = 0.0f;
#pragma unroll
        for (int t = 0; t < 12; ++t) {
            s += (ov[t].x - ev[t].x) + (ov[t].y - ev[t].y)
               + (ov[t].z - ev[t].z) + (ov[t].w - ev[t].w);
        }
        g[idx] = s * (1.0f / 48.0f);
    }
}

// Kernel 2: loss[i,j] = sum over {l,r,u,d} of (g[i,j] - g_pad[neighbor])^2
// Zero padding: out-of-bounds neighbor contributes 0 (so diff = g[i,j]).
__global__ void __launch_bounds__(256)
stencil_loss_kernel(const float* __restrict__ g,
                    float* __restrict__ out, int total) {
    int idx = blockIdx.x * blockDim.x + threadIdx.x;
    if (idx >= total) return;
    int j = idx & (PW - 1);
    int i = (idx >> 7) & (PH - 1);

    float c = g[idx];
    float l = (j > 0)      ? g[idx - 1]  : 0.0f;
    float r = (j < PW - 1) ? g[idx + 1]  : 0.0f;
    float u = (i > 0)      ? g[idx - PW] : 0.0f;
    float d = (i < PH - 1) ? g[idx + PW] : 0.0f;

    float dl = c - l, dr = c - r, du = c - u, dd = c - d;
    out[idx] = dl * dl + dr * dr + du * du + dd * dd;
}

extern "C" void kernel_launch(void* const* d_in, const int* in_sizes, int n_in,
                              void* d_out, int out_size, void* d_ws, size_t ws_size,
                              hipStream_t stream) {
    const float* orig = (const float*)d_in[0];
    const float* enh  = (const float*)d_in[1];
    float* out = (float*)d_out;
    float* g   = (float*)d_ws;  // 32*128*128 floats = 2 MB scratch

    const int batch = in_sizes[0] / (CC * HH * WW);   // 32
    const int total = batch * PH * PW;                // 524288

    // Persistent: 512 blocks (2 per CU), each thread handles 4 pooled cells.
    pool_diff_kernel<<<512, 256, 0, stream>>>(orig, enh, g, total);

    const int block = 256;
    const int grid = (total + block - 1) / block;     // 2048
    stencil_loss_kernel<<<grid, block, 0, stream>>>(g, out, total);
}